// Round 1
// baseline (51.327 us; speedup 1.0000x reference)
//
#include <hip/hip_runtime.h>

#define POOL 7
#define FH 14
#define FW 14
#define CCH 1024
#define IMG_SZ 224.0f

__global__ __launch_bounds__(256) void roi_pool_kernel(
    const float* __restrict__ img, const float* __restrict__ rois,
    float* __restrict__ out)
{
    const int b  = blockIdx.y;
    const int pq = blockIdx.x;       // 0..48
    const int py = pq / POOL;
    const int px = pq - py * POOL;
    const int t  = threadIdx.x;      // 0..255 -> channels 4t..4t+3

    const float scale = (float)FH / IMG_SZ;   // 0.0625 exact
    const float r0 = rois[b*4+0];
    const float r1 = rois[b*4+1];
    const float r2 = rois[b*4+2];
    const float r3 = rois[b*4+3];

    int ymin = (int)floorf(r0 * scale);
    ymin = min(max(ymin, 0), FH-1);
    int xmin = (int)floorf(r1 * scale);
    xmin = min(max(xmin, 0), FW-1);
    int ymax = (int)floorf(r2 * scale);
    ymax = min(max(ymax, ymin), FH-1);
    int xmax = (int)floorf(r3 * scale);
    xmax = min(max(xmax, xmin), FW-1);

    // y axis coords (mirror reference _axis_coords, f32 ops)
    float ny = (float)(ymax - ymin + 1);
    float sy = (float)py * (ny / (float)POOL);
    int   iy0 = (int)sy;                     // trunc == floor (sy >= 0)
    int   iy1 = min(iy0 + 1, ymax - ymin);
    float ly  = sy - (float)iy0;
    const int y0 = ymin + iy0, y1 = ymin + iy1;

    // x axis coords
    float nx = (float)(xmax - xmin + 1);
    float sx = (float)px * (nx / (float)POOL);
    int   ix0 = (int)sx;
    int   ix1 = min(ix0 + 1, xmax - xmin);
    float lx  = sx - (float)ix0;
    const int x0 = xmin + ix0, x1 = xmin + ix1;

    const size_t base = (size_t)b * (FH * FW * CCH);
    const float4* p00 = (const float4*)(img + base + ((size_t)(y0*FW + x0)) * CCH) + t;
    const float4* p01 = (const float4*)(img + base + ((size_t)(y0*FW + x1)) * CCH) + t;
    const float4* p10 = (const float4*)(img + base + ((size_t)(y1*FW + x0)) * CCH) + t;
    const float4* p11 = (const float4*)(img + base + ((size_t)(y1*FW + x1)) * CCH) + t;

    float4 v00 = *p00;
    float4 v01 = *p01;
    float4 v10 = *p10;
    float4 v11 = *p11;

    float4 r;
    {
        float top = v00.x + (v01.x - v00.x) * lx;
        float bot = v10.x + (v11.x - v10.x) * lx;
        r.x = top + (bot - top) * ly;
    }
    {
        float top = v00.y + (v01.y - v00.y) * lx;
        float bot = v10.y + (v11.y - v10.y) * lx;
        r.y = top + (bot - top) * ly;
    }
    {
        float top = v00.z + (v01.z - v00.z) * lx;
        float bot = v10.z + (v11.z - v10.z) * lx;
        r.z = top + (bot - top) * ly;
    }
    {
        float top = v00.w + (v01.w - v00.w) * lx;
        float bot = v10.w + (v11.w - v10.w) * lx;
        r.w = top + (bot - top) * ly;
    }

    float4* po = (float4*)(out + ((size_t)((b * POOL + py) * POOL + px)) * CCH) + t;
    *po = r;
}

extern "C" void kernel_launch(void* const* d_in, const int* in_sizes, int n_in,
                              void* d_out, int out_size, void* d_ws, size_t ws_size,
                              hipStream_t stream) {
    const float* img  = (const float*)d_in[0];
    const float* rois = (const float*)d_in[1];
    float* out = (float*)d_out;

    dim3 grid(POOL * POOL, 512 /*B*/);
    dim3 block(256);
    hipLaunchKernelGGL(roi_pool_kernel, grid, block, 0, stream, img, rois, out);
}

// Round 2
// 31.129 us; speedup vs baseline: 1.6489x; 1.6489x over previous
//
#include <hip/hip_runtime.h>

#define POOL 7
#define FH 14
#define FW 14
#define CCH 1024
#define IMG_SZ 224.0f
#define NB 512

// One block per (b, py) output row: 7 px cells x 1024 channels.
// Thread t owns channels 4t..4t+3 (float4, 16 B/lane, fully coalesced:
// each pixel access = 256 lanes x 16 B = 4 KB contiguous).
// All 28 corner loads are issued before any use -> deep MLP; overlapping
// corners across px dedup in L1/L2 of the owning CU/XCD.
__global__ __launch_bounds__(256) void roi_pool_row(
    const float* __restrict__ img, const float* __restrict__ rois,
    float* __restrict__ out)
{
    // XCD-aware swizzle: NWG = 512*7 = 3584 = 8*448, so the simple bijective
    // form is valid; all 7 rows of one batch land on the same XCD -> the
    // y-overlap between adjacent rows dedups in that XCD's private L2.
    const int NWG = NB * POOL;
    const int CPX = NWG / 8;
    int bid = blockIdx.x;
    int swz = (bid & 7) * CPX + (bid >> 3);
    const int b  = swz / POOL;
    const int py = swz - b * POOL;
    const int t  = threadIdx.x;

    const float scale = (float)FH / IMG_SZ;   // 0.0625 exact
    const float r0 = rois[b*4+0];
    const float r1 = rois[b*4+1];
    const float r2 = rois[b*4+2];
    const float r3 = rois[b*4+3];

    int ymin = min(max((int)floorf(r0 * scale), 0), FH-1);
    int xmin = min(max((int)floorf(r1 * scale), 0), FW-1);
    int ymax = min(max((int)floorf(r2 * scale), ymin), FH-1);
    int xmax = min(max((int)floorf(r3 * scale), xmin), FW-1);

    // y axis (mirrors reference _axis_coords in f32 exactly)
    float ny  = (float)(ymax - ymin + 1);
    float sy  = (float)py * (ny / (float)POOL);
    int   iy0 = (int)sy;
    int   iy1 = min(iy0 + 1, ymax - ymin);
    float ly  = sy - (float)iy0;
    const int y0 = ymin + iy0, y1 = ymin + iy1;

    const float nx7 = (float)(xmax - xmin + 1) / (float)POOL;

    const float* bimg = img + (size_t)b * (FH * FW * CCH);
    const float* row0 = bimg + (size_t)(y0 * FW) * CCH;
    const float* row1 = bimg + (size_t)(y1 * FW) * CCH;

    float4 v00[POOL], v01[POOL], v10[POOL], v11[POOL];
    float  lxv[POOL];

    #pragma unroll
    for (int px = 0; px < POOL; ++px) {
        float sx  = (float)px * nx7;
        int   ix0 = (int)sx;
        int   ix1 = min(ix0 + 1, xmax - xmin);
        lxv[px]   = sx - (float)ix0;
        const int x0 = xmin + ix0, x1 = xmin + ix1;
        v00[px] = *((const float4*)(row0 + (size_t)x0 * CCH) + t);
        v01[px] = *((const float4*)(row0 + (size_t)x1 * CCH) + t);
        v10[px] = *((const float4*)(row1 + (size_t)x0 * CCH) + t);
        v11[px] = *((const float4*)(row1 + (size_t)x1 * CCH) + t);
    }

    float4* orow = (float4*)(out + (size_t)((b * POOL + py) * POOL) * CCH);

    #pragma unroll
    for (int px = 0; px < POOL; ++px) {
        const float lx = lxv[px];
        float4 a = v00[px], bq = v01[px], c = v10[px], d = v11[px];
        float4 r;
        {
            float top = a.x + (bq.x - a.x) * lx;
            float bot = c.x + (d.x - c.x) * lx;
            r.x = top + (bot - top) * ly;
        }
        {
            float top = a.y + (bq.y - a.y) * lx;
            float bot = c.y + (d.y - c.y) * lx;
            r.y = top + (bot - top) * ly;
        }
        {
            float top = a.z + (bq.z - a.z) * lx;
            float bot = c.z + (d.z - c.z) * lx;
            r.z = top + (bot - top) * ly;
        }
        {
            float top = a.w + (bq.w - a.w) * lx;
            float bot = c.w + (d.w - c.w) * lx;
            r.w = top + (bot - top) * ly;
        }
        *(orow + (size_t)px * (CCH/4) + t) = r;
    }
}

extern "C" void kernel_launch(void* const* d_in, const int* in_sizes, int n_in,
                              void* d_out, int out_size, void* d_ws, size_t ws_size,
                              hipStream_t stream) {
    const float* img  = (const float*)d_in[0];
    const float* rois = (const float*)d_in[1];
    float* out = (float*)d_out;

    dim3 grid(NB * POOL);
    dim3 block(256);
    hipLaunchKernelGGL(roi_pool_row, grid, block, 0, stream, img, rois, out);
}

// Round 4
// 30.848 us; speedup vs baseline: 1.6638x; 1.0091x over previous
//
#include <hip/hip_runtime.h>

#define POOL 7
#define FH 14
#define FW 14
#define CCH 1024
#define IMG_SZ 224.0f
#define NB 512

typedef float f32x4 __attribute__((ext_vector_type(4)));

// One block per (b, py) output row: 7 px cells x 1024 channels.
// Thread t owns channels 4t..4t+3 (16 B/lane, fully coalesced).
// All 28 corner loads issued before any use -> deep MLP; overlapping
// corners dedup in L1/L2. Output stored non-temporally so the 103 MB
// write-once stream doesn't evict the input rows (cross-row L2 reuse).
__global__ __launch_bounds__(256) void roi_pool_row(
    const float* __restrict__ img, const float* __restrict__ rois,
    float* __restrict__ out)
{
    // XCD-aware swizzle: NWG = 3584 = 8*448 (divisible -> simple form is
    // bijective); all 7 rows of one batch land on the same XCD.
    const int NWG = NB * POOL;
    const int CPX = NWG / 8;
    int bid = blockIdx.x;
    int swz = (bid & 7) * CPX + (bid >> 3);
    const int b  = swz / POOL;
    const int py = swz - b * POOL;
    const int t  = threadIdx.x;

    const float scale = (float)FH / IMG_SZ;   // 0.0625 exact
    const float r0 = rois[b*4+0];
    const float r1 = rois[b*4+1];
    const float r2 = rois[b*4+2];
    const float r3 = rois[b*4+3];

    int ymin = min(max((int)floorf(r0 * scale), 0), FH-1);
    int xmin = min(max((int)floorf(r1 * scale), 0), FW-1);
    int ymax = min(max((int)floorf(r2 * scale), ymin), FH-1);
    int xmax = min(max((int)floorf(r3 * scale), xmin), FW-1);

    // y axis (mirrors reference _axis_coords in f32 exactly)
    float ny  = (float)(ymax - ymin + 1);
    float sy  = (float)py * (ny / (float)POOL);
    int   iy0 = (int)sy;
    int   iy1 = min(iy0 + 1, ymax - ymin);
    float ly  = sy - (float)iy0;
    const int y0 = ymin + iy0, y1 = ymin + iy1;

    const float nx7 = (float)(xmax - xmin + 1) / (float)POOL;

    const float* bimg = img + (size_t)b * (FH * FW * CCH);
    const float* row0 = bimg + (size_t)(y0 * FW) * CCH;
    const float* row1 = bimg + (size_t)(y1 * FW) * CCH;

    f32x4 v00[POOL], v01[POOL], v10[POOL], v11[POOL];
    float lxv[POOL];

    #pragma unroll
    for (int px = 0; px < POOL; ++px) {
        float sx  = (float)px * nx7;
        int   ix0 = (int)sx;
        int   ix1 = min(ix0 + 1, xmax - xmin);
        lxv[px]   = sx - (float)ix0;
        const int x0 = xmin + ix0, x1 = xmin + ix1;
        v00[px] = *((const f32x4*)(row0 + (size_t)x0 * CCH) + t);
        v01[px] = *((const f32x4*)(row0 + (size_t)x1 * CCH) + t);
        v10[px] = *((const f32x4*)(row1 + (size_t)x0 * CCH) + t);
        v11[px] = *((const f32x4*)(row1 + (size_t)x1 * CCH) + t);
    }

    f32x4* orow = (f32x4*)(out + (size_t)((b * POOL + py) * POOL) * CCH);

    #pragma unroll
    for (int px = 0; px < POOL; ++px) {
        const float lx = lxv[px];
        f32x4 a = v00[px], bq = v01[px], c = v10[px], d = v11[px];
        f32x4 top = a + (bq - a) * lx;
        f32x4 bot = c + (d - c) * lx;
        f32x4 r   = top + (bot - top) * ly;
        __builtin_nontemporal_store(r, orow + (size_t)px * (CCH/4) + t);
    }
}

extern "C" void kernel_launch(void* const* d_in, const int* in_sizes, int n_in,
                              void* d_out, int out_size, void* d_ws, size_t ws_size,
                              hipStream_t stream) {
    const float* img  = (const float*)d_in[0];
    const float* rois = (const float*)d_in[1];
    float* out = (float*)d_out;

    dim3 grid(NB * POOL);
    dim3 block(256);
    hipLaunchKernelGGL(roi_pool_row, grid, block, 0, stream, img, rois, out);
}